// Round 1
// 453.451 us; speedup vs baseline: 1.0295x; 1.0295x over previous
//
#include <hip/hip_runtime.h>

#define SEQ 512
#define EMB 8
#define NFAC 4

// ---------------------------------------------------------------------------
// ws layout (floats):
//   wkq  [0..63]    folded cross-attn query·Wk rows: scores[p][s]=wkq[p]·x[s]+csb[p]
//   csb  [64..71]
//   M0   [72..135]  Wout[:,0:4]·Wv0  (8x8)  -> qcr = bo + M0·u_f + M1·u_{4+f}
//   M1   [136..199] Wout[:,4:8]·Wv1  (8x8)     where u_p = (Σ_s e_p(s)·x_s)/Σ_s e_p(s)
//   bo   [200..207] ca_b_out + Wout·bv
// ---------------------------------------------------------------------------

// Precompute: one wave. Stage ALL weights into LDS in one cooperative load
// round (kills the serial single-lane HBM-latency chain of the old version),
// then compute the tiny self-attention + foldings lane-parallel.
__global__ void precompute_kernel(
    const float* __restrict__ Q,
    const float* __restrict__ sa_w_in, const float* __restrict__ sa_b_in,
    const float* __restrict__ sa_w_out, const float* __restrict__ sa_b_out,
    const float* __restrict__ ca_w_in, const float* __restrict__ ca_b_in,
    const float* __restrict__ ca_w_out, const float* __restrict__ ca_b_out,
    float* __restrict__ ws)
{
    const int t = threadIdx.x;
    __shared__ float sw[608];
    __shared__ float sqh[32], skh[32], svh[32], sctx[32], sQu[32], sqc[32];
    enum { OQ = 0, SWIN = 32, SBIN = 224, SWOUT = 248, SBOUT = 312,
           CWIN = 320, CBIN = 512, CWOUT = 536, CBOUT = 600 };

    for (int i = t; i < 32;  i += 64) sw[OQ + i]    = Q[i];
    for (int i = t; i < 192; i += 64) sw[SWIN + i]  = sa_w_in[i];
    for (int i = t; i < 24;  i += 64) sw[SBIN + i]  = sa_b_in[i];
    for (int i = t; i < 64;  i += 64) sw[SWOUT + i] = sa_w_out[i];
    if (t < 8) sw[SBOUT + t] = sa_b_out[t];
    for (int i = t; i < 192; i += 64) sw[CWIN + i]  = ca_w_in[i];
    for (int i = t; i < 24;  i += 64) sw[CBIN + i]  = ca_b_in[i];
    for (int i = t; i < 64;  i += 64) sw[CWOUT + i] = ca_w_out[i];
    if (t < 8) sw[CBOUT + t] = ca_b_out[t];
    __syncthreads();

    // M0/M1/bo — independent of the self-attention result.
    {
        const int e2 = t >> 3, e = t & 7;
        float m0 = 0.f, m1 = 0.f;
        #pragma unroll
        for (int d = 0; d < 4; ++d) {
            m0 += sw[CWOUT + e2 * 8 + d]     * sw[CWIN + (16 + d) * 8 + e];
            m1 += sw[CWOUT + e2 * 8 + 4 + d] * sw[CWIN + (20 + d) * 8 + e];
        }
        ws[72 + t]  = m0;
        ws[136 + t] = m1;
    }
    if (t < 8) {
        float a = sw[CBOUT + t];
        #pragma unroll
        for (int d = 0; d < 8; ++d) a += sw[CWOUT + t * 8 + d] * sw[CBIN + 16 + d];
        ws[200 + t] = a;
    }

    // self-attn projections qh/kh/vh: 32 lanes, one (l,j) each
    if (t < 32) {
        const int l = t >> 3, j = t & 7;
        float aq = sw[SBIN + j], ak = sw[SBIN + 8 + j], av = sw[SBIN + 16 + j];
        #pragma unroll
        for (int e = 0; e < 8; ++e) {
            const float q = sw[OQ + l * 8 + e];
            aq += q * sw[SWIN + j * 8 + e];
            ak += q * sw[SWIN + (8 + j) * 8 + e];
            av += q * sw[SWIN + (16 + j) * 8 + e];
        }
        sqh[t] = aq; skh[t] = ak; svh[t] = av;
    }
    __syncthreads();

    // per-(h,l) softmax over the 4 keys + context
    if (t < 8) {
        const int h = t >> 2, l = t & 3;
        float sc[4], mx = -1e30f;
        #pragma unroll
        for (int m = 0; m < 4; ++m) {
            float a = 0.f;
            #pragma unroll
            for (int d = 0; d < 4; ++d) a += sqh[l * 8 + h * 4 + d] * skh[m * 8 + h * 4 + d];
            sc[m] = 0.5f * a;
            mx = fmaxf(mx, sc[m]);
        }
        float ssum = 0.f;
        #pragma unroll
        for (int m = 0; m < 4; ++m) { sc[m] = __expf(sc[m] - mx); ssum += sc[m]; }
        const float inv = 1.f / ssum;
        #pragma unroll
        for (int d = 0; d < 4; ++d) {
            float a = 0.f;
            #pragma unroll
            for (int m = 0; m < 4; ++m) a += sc[m] * svh[m * 8 + h * 4 + d];
            sctx[l * 8 + h * 4 + d] = a * inv;
        }
    }
    __syncthreads();

    // Qu = ctx @ sa_w_out^T + sa_b_out
    if (t < 32) {
        const int l = t >> 3, e2 = t & 7;
        float a = sw[SBOUT + e2];
        #pragma unroll
        for (int e = 0; e < 8; ++e) a += sctx[l * 8 + e] * sw[SWOUT + e2 * 8 + e];
        sQu[l * 8 + e2] = a;
    }
    __syncthreads();

    // qc = Qu @ Wq_ca^T + bq_ca
    if (t < 32) {
        const int l = t >> 3, j = t & 7;
        float a = sw[CBIN + j];
        #pragma unroll
        for (int e = 0; e < 8; ++e) a += sQu[l * 8 + e] * sw[CWIN + j * 8 + e];
        sqc[l * 8 + j] = a;
    }
    __syncthreads();

    // wkq[p][e] and csb[p]
    {
        const int p = t >> 3, e = t & 7, h = p >> 2, f = p & 3;
        float a = 0.f;
        #pragma unroll
        for (int d = 0; d < 4; ++d)
            a += sqc[f * 8 + h * 4 + d] * sw[CWIN + (8 + h * 4 + d) * 8 + e];
        ws[p * 8 + e] = 0.5f * a;
    }
    if (t < 8) {
        const int p = t, h = p >> 2, f = p & 3;
        float a = 0.f;
        #pragma unroll
        for (int d = 0; d < 4; ++d) a += sqc[f * 8 + h * 4 + d] * sw[CBIN + 8 + h * 4 + d];
        ws[64 + p] = 0.5f * a;
    }
}

// ---------------------------------------------------------------------------
// Main fused kernel: one block per batch, 256 threads = 4 waves.
// Wave w owns cross-score rows p={2w,2w+1}, then sim row f=w.
// Phase A accumulates the exp-weighted x-SUM (Wv folded out of the s-loop):
//   u_p = (Σ_s e_p(s)·x_s) / (Σ_s e_p(s));  qcr_f = bo + M0·u_f + M1·u_{4+f}
// ---------------------------------------------------------------------------
__global__ __launch_bounds__(256, 4) void fused_kernel(
    const float* __restrict__ x,
    const float* __restrict__ r_w1, const float* __restrict__ r_b1,
    const float* __restrict__ r_w2, const float* __restrict__ r_b2,
    const float* __restrict__ ws,
    float* __restrict__ out, float* __restrict__ sim_out)
{
    const int b = blockIdx.x;
    const int tid = threadIdx.x;
    const int w = __builtin_amdgcn_readfirstlane(tid >> 6);
    const int lane = tid & 63;

    __shared__ float4 su4[16];    // normalized u rows [p][e], 2 float4 per p
    __shared__ float sff[4][8];   // final_factors [f][e]

    const float* xb = x + (size_t)b * (SEQ * EMB);

    // wave-uniform score weights -> SGPRs
    const int p0 = 2 * w, p1 = 2 * w + 1;
    float wq0[8], wq1[8];
    #pragma unroll
    for (int e = 0; e < 8; ++e) { wq0[e] = ws[p0 * 8 + e]; wq1[e] = ws[p1 * 8 + e]; }
    const float cb0 = ws[64 + p0], cb1 = ws[64 + p1];

    // ---- phase A: x load + cross scores + exp + weighted-x accumulation
    float xr[8][8];
    float xa0[8] = {0.f,0.f,0.f,0.f,0.f,0.f,0.f,0.f};
    float xa1[8] = {0.f,0.f,0.f,0.f,0.f,0.f,0.f,0.f};
    float sum0 = 0.f, sum1 = 0.f;
    #pragma unroll
    for (int j = 0; j < 8; ++j) {
        const int s = lane + 64 * j;
        const float4* xp = (const float4*)(xb + s * 8);
        float4 lo = xp[0], hi = xp[1];
        xr[j][0] = lo.x; xr[j][1] = lo.y; xr[j][2] = lo.z; xr[j][3] = lo.w;
        xr[j][4] = hi.x; xr[j][5] = hi.y; xr[j][6] = hi.z; xr[j][7] = hi.w;
        float sc0 = cb0, sc1 = cb1;
        #pragma unroll
        for (int e = 0; e < 8; ++e) { sc0 += wq0[e] * xr[j][e]; sc1 += wq1[e] * xr[j][e]; }
        const float e0 = __expf(sc0), e1 = __expf(sc1);
        sum0 += e0; sum1 += e1;
        #pragma unroll
        for (int e = 0; e < 8; ++e) {
            xa0[e] += e0 * xr[j][e];
            xa1[e] += e1 * xr[j][e];
        }
    }
    // butterfly reduce 18 accumulators across the wave
    #pragma unroll
    for (int m = 1; m < 64; m <<= 1) {
        sum0 += __shfl_xor(sum0, m, 64);
        sum1 += __shfl_xor(sum1, m, 64);
        #pragma unroll
        for (int e = 0; e < 8; ++e) {
            xa0[e] += __shfl_xor(xa0[e], m, 64);
            xa1[e] += __shfl_xor(xa1[e], m, 64);
        }
    }
    if (lane == 0) {
        const float i0 = 1.f / sum0, i1 = 1.f / sum1;
        su4[2 * p0]     = make_float4(xa0[0] * i0, xa0[1] * i0, xa0[2] * i0, xa0[3] * i0);
        su4[2 * p0 + 1] = make_float4(xa0[4] * i0, xa0[5] * i0, xa0[6] * i0, xa0[7] * i0);
        su4[2 * p1]     = make_float4(xa1[0] * i1, xa1[1] * i1, xa1[2] * i1, xa1[3] * i1);
        su4[2 * p1 + 1] = make_float4(xa1[4] * i1, xa1[5] * i1, xa1[6] * i1, xa1[7] * i1);
    }
    __syncthreads();

    // ---- phase B: qcr row f=w via folded M0/M1 (8 lanes compute, shfl bcast)
    const float* su = (const float*)su4;
    float u0[8], u1[8];
    #pragma unroll
    for (int e = 0; e < 8; ++e) { u0[e] = su[w * 8 + e]; u1[e] = su[(4 + w) * 8 + e]; }
    const int e2 = lane & 7;
    float qv = ws[200 + e2];
    #pragma unroll
    for (int e = 0; e < 8; ++e)
        qv += ws[72 + e2 * 8 + e] * u0[e] + ws[136 + e2 * 8 + e] * u1[e];
    float qcr[8];
    #pragma unroll
    for (int e = 0; e < 8; ++e) qcr[e] = __shfl(qv, e, 64);

    // ---- phase C: similarity row f=w, write raw sim, fused softmax + ff
    float facc[8] = {0.f,0.f,0.f,0.f,0.f,0.f,0.f,0.f};
    float fsum = 0.f;
    float* simb = sim_out + (size_t)b * (NFAC * SEQ) + w * SEQ;
    #pragma unroll
    for (int j = 0; j < 8; ++j) {
        const int s = lane + 64 * j;
        float sim = 0.f;
        #pragma unroll
        for (int e = 0; e < 8; ++e) sim += qcr[e] * xr[j][e];
        simb[s] = sim;
        const float ez = __expf(sim);
        fsum += ez;
        #pragma unroll
        for (int e = 0; e < 8; ++e) facc[e] += ez * xr[j][e];
    }
    #pragma unroll
    for (int m = 1; m < 64; m <<= 1) {
        fsum += __shfl_xor(fsum, m, 64);
        #pragma unroll
        for (int e = 0; e < 8; ++e) facc[e] += __shfl_xor(facc[e], m, 64);
    }
    if (lane == 0) {
        const float inv = 1.f / fsum;
        #pragma unroll
        for (int e = 0; e < 8; ++e) sff[w][e] = facc[e] * inv;
    }
    __syncthreads();

    // ---- phase D: tiny MLP (wave 0, lanes 0..15), out[b]
    if (tid < 16) {
        float a = r_b1[tid];
        const float* fusedp = &sff[0][0];
        const float4* w1p = (const float4*)(r_w1 + tid * 32);
        #pragma unroll
        for (int k = 0; k < 8; ++k) {
            float4 ww = w1p[k];
            a += ww.x * fusedp[4 * k + 0] + ww.y * fusedp[4 * k + 1]
               + ww.z * fusedp[4 * k + 2] + ww.w * fusedp[4 * k + 3];
        }
        a = fmaxf(a, 0.f);
        float v = a * r_w2[tid];
        v += __shfl_xor(v, 1, 64);
        v += __shfl_xor(v, 2, 64);
        v += __shfl_xor(v, 4, 64);
        v += __shfl_xor(v, 8, 64);
        if (tid == 0) out[b] = v + r_b2[0];
    }
}

extern "C" void kernel_launch(void* const* d_in, const int* in_sizes, int n_in,
                              void* d_out, int out_size, void* d_ws, size_t ws_size,
                              hipStream_t stream) {
    const float* x        = (const float*)d_in[0];
    const float* Q        = (const float*)d_in[1];
    const float* sa_w_in  = (const float*)d_in[2];
    const float* sa_b_in  = (const float*)d_in[3];
    const float* sa_w_out = (const float*)d_in[4];
    const float* sa_b_out = (const float*)d_in[5];
    const float* ca_w_in  = (const float*)d_in[6];
    const float* ca_b_in  = (const float*)d_in[7];
    const float* ca_w_out = (const float*)d_in[8];
    const float* ca_b_out = (const float*)d_in[9];
    const float* r_w1     = (const float*)d_in[10];
    const float* r_b1     = (const float*)d_in[11];
    const float* r_w2     = (const float*)d_in[12];
    const float* r_b2     = (const float*)d_in[13];

    float* out = (float*)d_out;
    const int B = in_sizes[0] / (SEQ * EMB);
    float* sim = out + B;            // d_out = [out (B), similarity (B*F*S)]
    float* ws  = (float*)d_ws;       // 208 floats: wkq[64], csb[8], M0[64], M1[64], bo[8]

    precompute_kernel<<<1, 64, 0, stream>>>(Q, sa_w_in, sa_b_in, sa_w_out, sa_b_out,
                                            ca_w_in, ca_b_in, ca_w_out, ca_b_out, ws);
    fused_kernel<<<B, 256, 0, stream>>>(x, r_w1, r_b1, r_w2, r_b2, ws, out, sim);
}